// Round 3
// baseline (584.134 us; speedup 1.0000x reference)
//
#include <hip/hip_runtime.h>

// Problem constants (fixed by the reference's setup_inputs)
#define NN   100000      // nodes
#define EE   1600000     // num_edge
#define EROW 4800000     // edge_index row length (3*NUM_EDGE)

__device__ __forceinline__ float4 ld4(const float* p){ return *(const float4*)p; }

// ---------------------------------------------------------------------------
// Tiled fp32 SGEMM, double-buffered LDS, one barrier per K-tile.
// out[M x Ncols] = act( A[M x K] @ B[Ncols x K]^T + bias )
// BM=BN=128, BK=16, 256 threads, 8x8 per thread (split 4+4 halves).
// MODE 0: A gathered from trace_all (two L-halves); relu output.
// MODE 3: plain A; epilogue L2-normalizes each output row (needs Ncols==128).
// MODE 2: B is repacked view of W_fc1 (rows 0-63 = left half, 64-127 = right
//         half); bias = b_fc1 added to first 64 output cols only.
// ---------------------------------------------------------------------------
template<int MODE>
__global__ __launch_bounds__(256, 2)
void gemm_k(const float* __restrict__ A, const float* __restrict__ B,
            const float* __restrict__ bias, float* __restrict__ out,
            int M, int Ncols, int K)
{
    __shared__ float As[2][16][132];   // [buf][k][m], pad 132
    __shared__ float Bs[2][16][132];   // [buf][k][n]

    const int t  = threadIdx.x;
    const int tx = t & 15;          // n-direction
    const int ty = t >> 4;          // m-direction
    const int mBase = blockIdx.x * 128;
    const int nBase = blockIdx.y * 128;

    float acc[8][8];
#pragma unroll
    for (int i = 0; i < 8; ++i)
#pragma unroll
        for (int j = 0; j < 8; ++j) acc[i][j] = 0.f;

    const int rA = t >> 1;          // 0..127: tile row for loads
    const int hk = (t & 1) * 8;     // which 8-float half of the 16-wide k chunk
    int mrow = mBase + rA; if (mrow >= M) mrow = M - 1;   // clamp tail rows
    const int nrow = nBase + rA;    // Ncols multiple of 128 -> in range

    auto loadA = [&](int k0, float4& x0, float4& x1) {
        if (MODE == 0) {
            // x[n][k] = trace_all[k>>7][n][k&127]
            const float* src = A + (size_t)(k0 >> 7) * (NN * 128)
                                 + (size_t)mrow * 128 + (k0 & 127);
            x0 = ld4(src); x1 = ld4(src + 4);
        } else {
            const float* src = A + (size_t)mrow * K + k0;
            x0 = ld4(src); x1 = ld4(src + 4);
        }
    };
    auto loadB = [&](int k0, float4& x0, float4& x1) {
        if (MODE == 2) {
            // B[j][k] = W_fc1[j&63][(j>>6)*128 + k], K=128
            const float* src = B + (size_t)(nrow & 63) * 256 + (nrow >> 6) * 128 + k0;
            x0 = ld4(src); x1 = ld4(src + 4);
        } else {
            const float* src = B + (size_t)nrow * K + k0;
            x0 = ld4(src); x1 = ld4(src + 4);
        }
    };

    const int kIters = K / 16;
    float4 a0, a1, b0, b1;
    loadA(hk, a0, a1);
    loadB(hk, b0, b1);

    int buf = 0;
    for (int kt = 0; kt < kIters; ++kt) {
        // Stage current tile regs -> LDS[buf] (other buffer may still be read
        // by slower waves — safe, different buffer).
        As[buf][hk+0][rA] = a0.x; As[buf][hk+1][rA] = a0.y;
        As[buf][hk+2][rA] = a0.z; As[buf][hk+3][rA] = a0.w;
        As[buf][hk+4][rA] = a1.x; As[buf][hk+5][rA] = a1.y;
        As[buf][hk+6][rA] = a1.z; As[buf][hk+7][rA] = a1.w;
        Bs[buf][hk+0][rA] = b0.x; Bs[buf][hk+1][rA] = b0.y;
        Bs[buf][hk+2][rA] = b0.z; Bs[buf][hk+3][rA] = b0.w;
        Bs[buf][hk+4][rA] = b1.x; Bs[buf][hk+5][rA] = b1.y;
        Bs[buf][hk+6][rA] = b1.z; Bs[buf][hk+7][rA] = b1.w;
        __syncthreads();

        // Prefetch next global tile while computing this one.
        const int knext = (kt + 1 < kIters) ? (kt + 1) * 16 + hk : hk;
        float4 na0, na1, nb0, nb1;
        loadA(knext, na0, na1);
        loadB(knext, nb0, nb1);

#pragma unroll
        for (int k = 0; k < 16; ++k) {
            float4 av0 = ld4(&As[buf][k][ty * 4]);
            float4 av1 = ld4(&As[buf][k][64 + ty * 4]);
            float4 bv0 = ld4(&Bs[buf][k][tx * 4]);
            float4 bv1 = ld4(&Bs[buf][k][64 + tx * 4]);
            float am[8] = {av0.x, av0.y, av0.z, av0.w, av1.x, av1.y, av1.z, av1.w};
            float bn[8] = {bv0.x, bv0.y, bv0.z, bv0.w, bv1.x, bv1.y, bv1.z, bv1.w};
#pragma unroll
            for (int i = 0; i < 8; ++i)
#pragma unroll
                for (int j = 0; j < 8; ++j)
                    acc[i][j] = fmaf(am[i], bn[j], acc[i][j]);
        }
        a0 = na0; a1 = na1; b0 = nb0; b1 = nb1;
        buf ^= 1;
    }

    // ---- Epilogue ----
    float nrm[8];
    if (MODE == 3) {
        // Row L2 norm: each row's 128 cols live in the 16 lanes sharing ty.
#pragma unroll
        for (int i = 0; i < 8; ++i) {
            float ssq = 0.f;
#pragma unroll
            for (int j = 0; j < 8; ++j) ssq = fmaf(acc[i][j], acc[i][j], ssq);
#pragma unroll
            for (int off = 1; off < 16; off <<= 1) ssq += __shfl_xor(ssq, off, 16);
            nrm[i] = fmaxf(sqrtf(ssq), 1e-12f);
        }
    }

    float4 bb = make_float4(0.f, 0.f, 0.f, 0.f);
    if (MODE == 2) bb = ld4(&bias[tx * 4]);   // first-half cols get b_fc1

#pragma unroll
    for (int i = 0; i < 8; ++i) {
        const int mloc = (i < 4) ? (ty * 4 + i) : (64 + ty * 4 + (i - 4));
        const int m = mBase + mloc;
        if (m < M) {
            float* orow = out + (size_t)m * Ncols + nBase;
            float v0x = acc[i][0], v0y = acc[i][1], v0z = acc[i][2], v0w = acc[i][3];
            float v1x = acc[i][4], v1y = acc[i][5], v1z = acc[i][6], v1w = acc[i][7];
            if (MODE == 2) { v0x += bb.x; v0y += bb.y; v0z += bb.z; v0w += bb.w; }
            if (MODE == 0) {
                v0x = fmaxf(v0x, 0.f); v0y = fmaxf(v0y, 0.f);
                v0z = fmaxf(v0z, 0.f); v0w = fmaxf(v0w, 0.f);
                v1x = fmaxf(v1x, 0.f); v1y = fmaxf(v1y, 0.f);
                v1z = fmaxf(v1z, 0.f); v1w = fmaxf(v1w, 0.f);
            }
            if (MODE == 3) {
                v0x /= nrm[i]; v0y /= nrm[i]; v0z /= nrm[i]; v0w /= nrm[i];
                v1x /= nrm[i]; v1y /= nrm[i]; v1z /= nrm[i]; v1w /= nrm[i];
            }
            *(float4*)&orow[tx * 4]      = make_float4(v0x, v0y, v0z, v0w);
            *(float4*)&orow[64 + tx * 4] = make_float4(v1x, v1y, v1z, v1w);
        }
    }
}

// ---------------------------------------------------------------------------
// Edge kernel: 128 edges/block, 16 lanes per edge, 8 edges per lane-group.
// All 16 gather loads issued before first use -> deep MLP (memory-level
// parallelism) against the L3-resident p table.
// v = relu(p[src][0:64] + p[dst][64:128]); s = W_fc2 @ v + b_fc2;
// active = (s0+g0 >= s1+g1); train_mask = [active, 1-active, 1-active].
// ---------------------------------------------------------------------------
#define EPB 128
__global__ __launch_bounds__(256, 4)
void edge_k(const float* __restrict__ p, const int* __restrict__ ei,
            const float* __restrict__ gum, const float* __restrict__ W2,
            const float* __restrict__ b2, float* __restrict__ out)
{
    __shared__ int   sidx[EPB];
    __shared__ int   didx[EPB];
    __shared__ float gl[2 * EPB];
    __shared__ float act[EPB];

    const int t  = threadIdx.x;
    const int e0 = blockIdx.x * EPB;

    if (t < EPB) sidx[t] = ei[e0 + t];
    else         didx[t - EPB] = ei[EROW + e0 + (t - EPB)];
    gl[t] = gum[(size_t)e0 * 2 + t];
    __syncthreads();

    const int j   = t & 15;    // lane within edge group
    const int grp = t >> 4;    // 16 groups, 8 edges each
    const float4 w0 = ld4(&W2[j * 4]);
    const float4 w1 = ld4(&W2[64 + j * 4]);
    const float b20 = b2[0], b21 = b2[1];

    float4 pa[8], pb[8];
#pragma unroll
    for (int it = 0; it < 8; ++it) {
        const int el = grp * 8 + it;
        pa[it] = ld4(&p[(size_t)sidx[el] * 128 + j * 4]);
        pb[it] = ld4(&p[(size_t)didx[el] * 128 + 64 + j * 4]);
    }

#pragma unroll
    for (int it = 0; it < 8; ++it) {
        const int el = grp * 8 + it;
        const float r0 = fmaxf(pa[it].x + pb[it].x, 0.f);
        const float r1 = fmaxf(pa[it].y + pb[it].y, 0.f);
        const float r2 = fmaxf(pa[it].z + pb[it].z, 0.f);
        const float r3 = fmaxf(pa[it].w + pb[it].w, 0.f);
        float s0 = r0 * w0.x + r1 * w0.y + r2 * w0.z + r3 * w0.w;
        float s1 = r0 * w1.x + r1 * w1.y + r2 * w1.z + r3 * w1.w;
#pragma unroll
        for (int off = 1; off < 16; off <<= 1) {
            s0 += __shfl_xor(s0, off, 16);
            s1 += __shfl_xor(s1, off, 16);
        }
        if (j == 0) {
            const float sc0 = s0 + b20 + gl[el * 2];
            const float sc1 = s1 + b21 + gl[el * 2 + 1];
            act[el] = (sc0 >= sc1) ? 1.f : 0.f;   // argmax ties -> index 0
        }
    }
    __syncthreads();

    if (t < EPB) {
        const float a = act[t];
        const size_t e = (size_t)e0 + t;
        out[e]                  = a;
        out[EE + e]             = 1.f - a;
        out[2 * (size_t)EE + e] = 1.f - a;
    }
}

// ---------------------------------------------------------------------------
extern "C" void kernel_launch(void* const* d_in, const int* in_sizes, int n_in,
                              void* d_out, int out_size, void* d_ws, size_t ws_size,
                              hipStream_t stream)
{
    const float* trace  = (const float*)d_in[0];   // (2,100000,128)
    const float* W_lin  = (const float*)d_in[1];   // (256,256)
    const float* W_lin2 = (const float*)d_in[2];   // (128,256)
    const float* W_fc1  = (const float*)d_in[3];   // (64,256)
    const float* b_fc1  = (const float*)d_in[4];   // (64,)
    const float* W_fc2  = (const float*)d_in[5];   // (2,64)
    const float* b_fc2  = (const float*)d_in[6];   // (2,)
    const float* gum    = (const float*)d_in[7];   // (1600000,2)
    const int*   ei     = (const int*)  d_in[8];   // (2,4800000)
    float*       out    = (float*)d_out;           // (4800000,)

    // Workspace: h [100k x 256] at 0 (102.4 MB); mvc [100k x 128] after it
    // (51.2 MB); p [100k x 128] reuses h's region (h dead after GEMM2).
    float* h   = (float*)d_ws;
    float* mvc = (float*)((char*)d_ws + (size_t)NN * 256 * 4);
    float* p   = (float*)d_ws;

    const int mBlocks = (NN + 127) / 128;   // 782

    // h = relu(x @ W_lin^T)
    gemm_k<0><<<dim3(mBlocks, 2), 256, 0, stream>>>(trace, W_lin, nullptr, h, NN, 256, 256);
    // mvc = normalize_rows(h @ W_lin2^T)   (norm fused into epilogue)
    gemm_k<3><<<dim3(mBlocks, 1), 256, 0, stream>>>(h, W_lin2, nullptr, mvc, NN, 128, 256);
    // p[n] = [W_fc1_left @ mvcn + b_fc1 | W_fc1_right @ mvcn]
    gemm_k<2><<<dim3(mBlocks, 1), 256, 0, stream>>>(mvc, W_fc1, b_fc1, p, NN, 128, 128);
    // per-edge score + hard mask
    edge_k<<<EE / 128, 256, 0, stream>>>(p, ei, gum, W_fc2, b_fc2, out);
}

// Round 4
// 417.005 us; speedup vs baseline: 1.4008x; 1.4008x over previous
//
#include <hip/hip_runtime.h>

// Problem constants (fixed by the reference's setup_inputs)
#define NN   100000      // nodes
#define EE   1600000     // num_edge
#define EROW 4800000     // edge_index row length (3*NUM_EDGE)

typedef _Float16 half8 __attribute__((ext_vector_type(8)));
typedef float    f32x4 __attribute__((ext_vector_type(4)));

__device__ __forceinline__ float4 ld4(const float* p){ return *(const float4*)p; }

// Split fp32 -> (hi fp16) + (lo fp16, scaled by 2048). Packed as dword lo16=hi, hi16=lo.
__device__ __forceinline__ unsigned splitf(float v) {
    _Float16 h = (_Float16)v;
    float r = v - (float)h;
    _Float16 l = (_Float16)(r * 2048.0f);
    union { _Float16 f; unsigned short u; } uh, ul;
    uh.f = h; ul.f = l;
    return (unsigned)uh.u | ((unsigned)ul.u << 16);
}

// ---------------------------------------------------------------------------
// Weight prep: split W_lin (256x256), W_lin2 (128x256), repacked W_fc1
// (128x128: row j = W_fc1[j&63][(j>>6)*128 ..]) into interleaved half2 planes.
// ---------------------------------------------------------------------------
__global__ __launch_bounds__(256)
void prep_w(const float* __restrict__ W1, const float* __restrict__ W2,
            const float* __restrict__ W3, unsigned* __restrict__ o1,
            unsigned* __restrict__ o2, unsigned* __restrict__ o3)
{
    int idx = blockIdx.x * 256 + threadIdx.x;   // 448 blocks = 114688 threads
    if (idx < 65536) {
        o1[idx] = splitf(W1[idx]);
    } else if (idx < 98304) {
        int i = idx - 65536;
        o2[i] = splitf(W2[i]);
    } else {
        int i = idx - 98304;
        int j = i >> 7, k = i & 127;
        o3[i] = splitf(W3[(j & 63) * 256 + (j >> 6) * 128 + k]);
    }
}

// ---------------------------------------------------------------------------
// MFMA split-fp16 GEMM: C[M x No] = A[M x K] @ B[No x K]^T (+epilogue).
// 256 thr = 4 waves, wave grid 2x2, wave tile 64x64 (4x4 of 16x16x32 f16).
// 3 MFMA passes: acc_hi += Ah*Bh; acc_mid += Ah*Bl + Al*Bh; C = hi + mid/2048.
// SRCA 0: A = trace fp32 (gathered 2-plane, split on the fly). 1: split plane.
// EPI  0: relu, store split plane. 1: row-L2-normalize, store split plane.
//      2: += b_fc1 on cols 0-63, store fp32.
// ---------------------------------------------------------------------------
template<int SRCA, int EPI>
__global__ __launch_bounds__(256, 2)
void gemm_mfma(const void* __restrict__ Asrc, const unsigned* __restrict__ Bw,
               const float* __restrict__ bias, unsigned* __restrict__ outS,
               float* __restrict__ outF, int M, int K, int No)
{
    // 40-halfword rows: 80 B stride -> 16B-aligned b128 frag reads, 2-way banks.
    __shared__ __align__(16) _Float16 Ah[128][40];
    __shared__ __align__(16) _Float16 Al[128][40];
    __shared__ __align__(16) _Float16 Bh[128][40];
    __shared__ __align__(16) _Float16 Bl[128][40];
    __shared__ float sq[128][2];   // EPI==1 cross-wave row ssq

    const int t     = threadIdx.x;
    const int wm    = (t >> 6) >> 1;   // wave m index (0..1)
    const int wn    = (t >> 6) & 1;    // wave n index (0..1)
    const int lane  = t & 63;
    const int lm    = lane & 15;
    const int q     = lane >> 4;
    const int mBase = blockIdx.x * 128;
    const int nBase = blockIdx.y * 128;

    const int srow = t >> 3;           // staging row 0..31 (+32*it)
    const int sseg = (t & 7) * 4;      // staging k-offset (elems)

    f32x4 aH[4][4], aM[4][4];
#pragma unroll
    for (int i = 0; i < 4; ++i)
#pragma unroll
        for (int j = 0; j < 4; ++j) {
            aH[i][j] = (f32x4){0.f, 0.f, 0.f, 0.f};
            aM[i][j] = (f32x4){0.f, 0.f, 0.f, 0.f};
        }

    uint2 sAh[4], sAl[4], sBh[4], sBl[4];

    auto loadStage = [&](int k0) {
#pragma unroll
        for (int it = 0; it < 4; ++it) {
            const int row = srow + it * 32;
            int rg = mBase + row; rg = rg < M ? rg : M - 1;
            if (SRCA == 0) {
                const int k = k0 + sseg;    // whole 32-chunk inside one L-plane
                const float* ap = (const float*)Asrc
                    + (size_t)(k >> 7) * ((size_t)NN * 128)
                    + (size_t)rg * 128 + (k & 127);
                float4 f = ld4(ap);
                unsigned p0 = splitf(f.x), p1 = splitf(f.y);
                unsigned p2 = splitf(f.z), p3 = splitf(f.w);
                sAh[it].x = (p0 & 0xffffu) | (p1 << 16);
                sAh[it].y = (p2 & 0xffffu) | (p3 << 16);
                sAl[it].x = (p0 >> 16) | (p1 & 0xffff0000u);
                sAl[it].y = (p2 >> 16) | (p3 & 0xffff0000u);
            } else {
                const unsigned* ap = (const unsigned*)Asrc + (size_t)rg * K + k0 + sseg;
                uint4 u = *(const uint4*)ap;
                sAh[it].x = (u.x & 0xffffu) | (u.y << 16);
                sAh[it].y = (u.z & 0xffffu) | (u.w << 16);
                sAl[it].x = (u.x >> 16) | (u.y & 0xffff0000u);
                sAl[it].y = (u.z >> 16) | (u.w & 0xffff0000u);
            }
            const unsigned* bp = Bw + (size_t)(nBase + row) * K + k0 + sseg;
            uint4 ub = *(const uint4*)bp;
            sBh[it].x = (ub.x & 0xffffu) | (ub.y << 16);
            sBh[it].y = (ub.z & 0xffffu) | (ub.w << 16);
            sBl[it].x = (ub.x >> 16) | (ub.y & 0xffff0000u);
            sBl[it].y = (ub.z >> 16) | (ub.w & 0xffff0000u);
        }
    };

    loadStage(0);
    const int nk = K / 32;
    for (int kt = 0; kt < nk; ++kt) {
        __syncthreads();   // prior iteration's frag reads done
#pragma unroll
        for (int it = 0; it < 4; ++it) {
            const int row = srow + it * 32;
            *(uint2*)&Ah[row][sseg] = sAh[it];
            *(uint2*)&Al[row][sseg] = sAl[it];
            *(uint2*)&Bh[row][sseg] = sBh[it];
            *(uint2*)&Bl[row][sseg] = sBl[it];
        }
        __syncthreads();   // writes visible
        if (kt + 1 < nk) loadStage((kt + 1) * 32);   // prefetch during MFMA

        half8 fAh[4], fAl[4], fBh[4], fBl[4];
#pragma unroll
        for (int i = 0; i < 4; ++i) {
            fAh[i] = *(const half8*)&Ah[wm * 64 + i * 16 + lm][q * 8];
            fAl[i] = *(const half8*)&Al[wm * 64 + i * 16 + lm][q * 8];
            fBh[i] = *(const half8*)&Bh[wn * 64 + i * 16 + lm][q * 8];
            fBl[i] = *(const half8*)&Bl[wn * 64 + i * 16 + lm][q * 8];
        }
#pragma unroll
        for (int i = 0; i < 4; ++i)
#pragma unroll
            for (int j = 0; j < 4; ++j)
                aH[i][j] = __builtin_amdgcn_mfma_f32_16x16x32_f16(fAh[i], fBh[j], aH[i][j], 0, 0, 0);
#pragma unroll
        for (int i = 0; i < 4; ++i)
#pragma unroll
            for (int j = 0; j < 4; ++j)
                aM[i][j] = __builtin_amdgcn_mfma_f32_16x16x32_f16(fAh[i], fBl[j], aM[i][j], 0, 0, 0);
#pragma unroll
        for (int i = 0; i < 4; ++i)
#pragma unroll
            for (int j = 0; j < 4; ++j)
                aM[i][j] = __builtin_amdgcn_mfma_f32_16x16x32_f16(fAl[i], fBh[j], aM[i][j], 0, 0, 0);
    }

    // Combine split accumulators: C = hi + mid/2048
    const float cM = 1.0f / 2048.0f;
#pragma unroll
    for (int i = 0; i < 4; ++i)
#pragma unroll
        for (int j = 0; j < 4; ++j)
            aH[i][j] = aH[i][j] + aM[i][j] * cM;

    float nm[4][4];
    if (EPI == 1) {
#pragma unroll
        for (int i = 0; i < 4; ++i)
#pragma unroll
            for (int r = 0; r < 4; ++r) {
                float s = 0.f;
#pragma unroll
                for (int j = 0; j < 4; ++j) { float x = aH[i][j][r]; s = fmaf(x, x, s); }
#pragma unroll
                for (int off = 1; off < 16; off <<= 1) s += __shfl_xor(s, off, 16);
                if (lm == 0) sq[wm * 64 + i * 16 + q * 4 + r][wn] = s;
            }
        __syncthreads();
#pragma unroll
        for (int i = 0; i < 4; ++i)
#pragma unroll
            for (int r = 0; r < 4; ++r) {
                const int rl = wm * 64 + i * 16 + q * 4 + r;
                nm[i][r] = fmaxf(sqrtf(sq[rl][0] + sq[rl][1]), 1e-12f);
            }
    }

    float bj[4] = {0.f, 0.f, 0.f, 0.f};
    if (EPI == 2 && wn == 0) {
#pragma unroll
        for (int j = 0; j < 4; ++j) bj[j] = bias[j * 16 + lm];
    }

#pragma unroll
    for (int i = 0; i < 4; ++i)
#pragma unroll
        for (int r = 0; r < 4; ++r) {
            const int m = mBase + wm * 64 + i * 16 + q * 4 + r;
            if (m < M) {
#pragma unroll
                for (int j = 0; j < 4; ++j) {
                    const int c = nBase + wn * 64 + j * 16 + lm;
                    float v = aH[i][j][r];
                    if (EPI == 0) { v = fmaxf(v, 0.f); outS[(size_t)m * No + c] = splitf(v); }
                    if (EPI == 1) { v = v / nm[i][r];  outS[(size_t)m * No + c] = splitf(v); }
                    if (EPI == 2) { v += bj[j];        outF[(size_t)m * No + c] = v; }
                }
            }
        }
}

// ---------------------------------------------------------------------------
// Edge kernel: 128 edges/block, 16 lanes per edge, 8 edges per lane-group.
// v = relu(p[src][0:64] + p[dst][64:128]); s = W_fc2 @ v + b_fc2;
// active = (s0+g0 >= s1+g1); train_mask = [active, 1-active, 1-active].
// ---------------------------------------------------------------------------
#define EPB 128
__global__ __launch_bounds__(256, 4)
void edge_k(const float* __restrict__ p, const int* __restrict__ ei,
            const float* __restrict__ gum, const float* __restrict__ W2,
            const float* __restrict__ b2, float* __restrict__ out)
{
    __shared__ int   sidx[EPB];
    __shared__ int   didx[EPB];
    __shared__ float gl[2 * EPB];
    __shared__ float act[EPB];

    const int t  = threadIdx.x;
    const int e0 = blockIdx.x * EPB;

    if (t < EPB) sidx[t] = ei[e0 + t];
    else         didx[t - EPB] = ei[EROW + e0 + (t - EPB)];
    gl[t] = gum[(size_t)e0 * 2 + t];
    __syncthreads();

    const int j   = t & 15;
    const int grp = t >> 4;
    const float4 w0 = ld4(&W2[j * 4]);
    const float4 w1 = ld4(&W2[64 + j * 4]);
    const float b20 = b2[0], b21 = b2[1];

    float4 pa[8], pb[8];
#pragma unroll
    for (int it = 0; it < 8; ++it) {
        const int el = grp * 8 + it;
        pa[it] = ld4(&p[(size_t)sidx[el] * 128 + j * 4]);
        pb[it] = ld4(&p[(size_t)didx[el] * 128 + 64 + j * 4]);
    }

#pragma unroll
    for (int it = 0; it < 8; ++it) {
        const int el = grp * 8 + it;
        const float r0 = fmaxf(pa[it].x + pb[it].x, 0.f);
        const float r1 = fmaxf(pa[it].y + pb[it].y, 0.f);
        const float r2 = fmaxf(pa[it].z + pb[it].z, 0.f);
        const float r3 = fmaxf(pa[it].w + pb[it].w, 0.f);
        float s0 = r0 * w0.x + r1 * w0.y + r2 * w0.z + r3 * w0.w;
        float s1 = r0 * w1.x + r1 * w1.y + r2 * w1.z + r3 * w1.w;
#pragma unroll
        for (int off = 1; off < 16; off <<= 1) {
            s0 += __shfl_xor(s0, off, 16);
            s1 += __shfl_xor(s1, off, 16);
        }
        if (j == 0) {
            const float sc0 = s0 + b20 + gl[el * 2];
            const float sc1 = s1 + b21 + gl[el * 2 + 1];
            act[el] = (sc0 >= sc1) ? 1.f : 0.f;
        }
    }
    __syncthreads();

    if (t < EPB) {
        const float a = act[t];
        const size_t e = (size_t)e0 + t;
        out[e]                  = a;
        out[EE + e]             = 1.f - a;
        out[2 * (size_t)EE + e] = 1.f - a;
    }
}

// ---------------------------------------------------------------------------
extern "C" void kernel_launch(void* const* d_in, const int* in_sizes, int n_in,
                              void* d_out, int out_size, void* d_ws, size_t ws_size,
                              hipStream_t stream)
{
    const float* trace  = (const float*)d_in[0];   // (2,100000,128)
    const float* W_lin  = (const float*)d_in[1];   // (256,256)
    const float* W_lin2 = (const float*)d_in[2];   // (128,256)
    const float* W_fc1  = (const float*)d_in[3];   // (64,256)
    const float* b_fc1  = (const float*)d_in[4];   // (64,)
    const float* W_fc2  = (const float*)d_in[5];   // (2,64)
    const float* b_fc2  = (const float*)d_in[6];   // (2,)
    const float* gum    = (const float*)d_in[7];   // (1600000,2)
    const int*   ei     = (const int*)  d_in[8];   // (2,4800000)
    float*       out    = (float*)d_out;           // (4800000,)

    // Workspace: h split-plane [NN x 256 dw] at 0 (102.4 MB); mvc split-plane
    // [NN x 128 dw] (51.2 MB); weight planes (459 KB). p (fp32) overlays h
    // (h dead after GEMM2). Total ~154.06 MB.
    char* ws = (char*)d_ws;
    unsigned* hpl  = (unsigned*)ws;
    unsigned* mpl  = (unsigned*)(ws + (size_t)NN * 256 * 4);
    unsigned* W1i  = (unsigned*)(ws + (size_t)NN * 256 * 4 + (size_t)NN * 128 * 4);
    unsigned* W2i  = W1i + 65536;
    unsigned* W3i  = W2i + 32768;
    float*    p    = (float*)ws;   // overlays h

    // Split weights into fp16 hi/lo interleaved planes.
    prep_w<<<448, 256, 0, stream>>>(W_lin, W_lin2, W_fc1, W1i, W2i, W3i);

    const int mB = (NN + 127) / 128;   // 782

    // h = relu(x @ W_lin^T), stored split
    gemm_mfma<0, 0><<<dim3(mB, 2), 256, 0, stream>>>(trace, W1i, nullptr, hpl, nullptr, NN, 256, 256);
    // mvc = normalize_rows(h @ W_lin2^T), stored split
    gemm_mfma<1, 1><<<dim3(mB, 1), 256, 0, stream>>>(hpl, W2i, nullptr, mpl, nullptr, NN, 256, 128);
    // p[n] = [W_fc1_left @ mvcn + b_fc1 | W_fc1_right @ mvcn], fp32
    gemm_mfma<1, 2><<<dim3(mB, 1), 256, 0, stream>>>(mpl, W3i, b_fc1, nullptr, p, NN, 128, 128);
    // per-edge score + hard mask
    edge_k<<<EE / EPB, 256, 0, stream>>>(p, ei, gum, W_fc2, b_fc2, out);
}

// Round 5
// 371.600 us; speedup vs baseline: 1.5719x; 1.1222x over previous
//
#include <hip/hip_runtime.h>

// Problem constants (fixed by the reference's setup_inputs)
#define NN   100000      // nodes
#define EE   1600000     // num_edge
#define EROW 4800000     // edge_index row length (3*NUM_EDGE)

typedef _Float16 half8 __attribute__((ext_vector_type(8)));
typedef _Float16 half4 __attribute__((ext_vector_type(4)));
typedef float    f32x4 __attribute__((ext_vector_type(4)));

__device__ __forceinline__ float4 ld4(const float* p){ return *(const float4*)p; }

// Split fp32 -> (hi fp16) + (lo fp16, scaled by 2048). Packed lo16=hi, hi16=lo.
__device__ __forceinline__ unsigned splitf(float v) {
    _Float16 h = (_Float16)v;
    float r = v - (float)h;
    _Float16 l = (_Float16)(r * 2048.0f);
    union { _Float16 f; unsigned short u; } uh, ul;
    uh.f = h; ul.f = l;
    return (unsigned)uh.u | ((unsigned)ul.u << 16);
}

// ---------------------------------------------------------------------------
// Weight prep: split W_lin (256x256), W_lin2 (128x256), repacked W_fc1
// (128x128: row j = W_fc1[j&63][(j>>6)*128 ..]) into interleaved half2 planes.
// ---------------------------------------------------------------------------
__global__ __launch_bounds__(256)
void prep_w(const float* __restrict__ W1, const float* __restrict__ W2,
            const float* __restrict__ W3, unsigned* __restrict__ o1,
            unsigned* __restrict__ o2, unsigned* __restrict__ o3)
{
    int idx = blockIdx.x * 256 + threadIdx.x;   // 448 blocks = 114688 threads
    if (idx < 65536) {
        o1[idx] = splitf(W1[idx]);
    } else if (idx < 98304) {
        int i = idx - 65536;
        o2[i] = splitf(W2[i]);
    } else {
        int i = idx - 98304;
        int j = i >> 7, k = i & 127;
        o3[i] = splitf(W3[(j & 63) * 256 + (j >> 6) * 128 + k]);
    }
}

// ---------------------------------------------------------------------------
// MFMA split-fp16 GEMM: C[M x No] = A[M x K] @ B[No x K]^T (+epilogue).
// 256 thr = 4 waves, wave grid 2x2, wave tile 64x64 (4x4 of 16x16x32 f16).
// 3 MFMA passes: acc_hi += Ah*Bh; acc_mid += Ah*Bl + Al*Bh; C = hi + mid/2048.
// LDS double-buffered (80 KB total), ONE barrier per K-tile.
// SRCA 0: A = trace fp32 (gathered 2-plane, split on the fly). 1: split plane.
// EPI  0: relu, store split plane. 1: row-L2-normalize, store split plane.
//      2: += b_fc1 on cols 0-63, store fp32 + fp16 copies.
// ---------------------------------------------------------------------------
template<int SRCA, int EPI>
__global__ __launch_bounds__(256, 2)
void gemm_mfma(const void* __restrict__ Asrc, const unsigned* __restrict__ Bw,
               const float* __restrict__ bias, unsigned* __restrict__ outS,
               float* __restrict__ outF, unsigned short* __restrict__ outH,
               int M, int K, int No)
{
    // 40-halfword rows: 80 B stride (16B-aligned), 2-way (free) bank tiling.
    __shared__ __align__(16) _Float16 Ah[2][128][40];
    __shared__ __align__(16) _Float16 Al[2][128][40];
    __shared__ __align__(16) _Float16 Bh[2][128][40];
    __shared__ __align__(16) _Float16 Bl[2][128][40];
    // EPI==1 cross-wave row-ssq scratch aliases Ah after the K-loop.
    float* sqv = (float*)&Ah[0][0][0];   // viewed as [128][2]

    const int t     = threadIdx.x;
    const int wm    = (t >> 6) >> 1;   // wave m index (0..1)
    const int wn    = (t >> 6) & 1;    // wave n index (0..1)
    const int lane  = t & 63;
    const int lm    = lane & 15;
    const int q     = lane >> 4;
    const int mBase = blockIdx.x * 128;
    const int nBase = blockIdx.y * 128;

    const int srow = t >> 3;           // staging row 0..31 (+32*it)
    const int sseg = (t & 7) * 4;      // staging k-offset (elems)

    f32x4 aH[4][4], aM[4][4];
#pragma unroll
    for (int i = 0; i < 4; ++i)
#pragma unroll
        for (int j = 0; j < 4; ++j) {
            aH[i][j] = (f32x4){0.f, 0.f, 0.f, 0.f};
            aM[i][j] = (f32x4){0.f, 0.f, 0.f, 0.f};
        }

    uint2 sAh[4], sAl[4], sBh[4], sBl[4];

    auto loadStage = [&](int k0) {
#pragma unroll
        for (int it = 0; it < 4; ++it) {
            const int row = srow + it * 32;
            int rg = mBase + row; rg = rg < M ? rg : M - 1;
            if (SRCA == 0) {
                const int k = k0 + sseg;    // whole 32-chunk inside one L-plane
                const float* ap = (const float*)Asrc
                    + (size_t)(k >> 7) * ((size_t)NN * 128)
                    + (size_t)rg * 128 + (k & 127);
                float4 f = ld4(ap);
                unsigned p0 = splitf(f.x), p1 = splitf(f.y);
                unsigned p2 = splitf(f.z), p3 = splitf(f.w);
                sAh[it].x = (p0 & 0xffffu) | (p1 << 16);
                sAh[it].y = (p2 & 0xffffu) | (p3 << 16);
                sAl[it].x = (p0 >> 16) | (p1 & 0xffff0000u);
                sAl[it].y = (p2 >> 16) | (p3 & 0xffff0000u);
            } else {
                const unsigned* ap = (const unsigned*)Asrc + (size_t)rg * K + k0 + sseg;
                uint4 u = *(const uint4*)ap;
                sAh[it].x = (u.x & 0xffffu) | (u.y << 16);
                sAh[it].y = (u.z & 0xffffu) | (u.w << 16);
                sAl[it].x = (u.x >> 16) | (u.y & 0xffff0000u);
                sAl[it].y = (u.z >> 16) | (u.w & 0xffff0000u);
            }
            const unsigned* bp = Bw + (size_t)(nBase + row) * K + k0 + sseg;
            uint4 ub = *(const uint4*)bp;
            sBh[it].x = (ub.x & 0xffffu) | (ub.y << 16);
            sBh[it].y = (ub.z & 0xffffu) | (ub.w << 16);
            sBl[it].x = (ub.x >> 16) | (ub.y & 0xffff0000u);
            sBl[it].y = (ub.z >> 16) | (ub.w & 0xffff0000u);
        }
    };

    loadStage(0);
    const int nk = K / 32;
    for (int kt = 0; kt < nk; ++kt) {
        const int b = kt & 1;
        // Write staged regs -> LDS[b]. Safe without a leading barrier: any
        // wave still reading buffer b is at iteration kt-2, separated from
        // this write by the kt-1 barrier it must pass after its reads.
#pragma unroll
        for (int it = 0; it < 4; ++it) {
            const int row = srow + it * 32;
            *(uint2*)&Ah[b][row][sseg] = sAh[it];
            *(uint2*)&Al[b][row][sseg] = sAl[it];
            *(uint2*)&Bh[b][row][sseg] = sBh[it];
            *(uint2*)&Bl[b][row][sseg] = sBl[it];
        }
        __syncthreads();
        if (kt + 1 < nk) loadStage((kt + 1) * 32);   // prefetch during MFMA

        half8 fAh[4], fAl[4], fBh[4], fBl[4];
#pragma unroll
        for (int i = 0; i < 4; ++i) {
            fAh[i] = *(const half8*)&Ah[b][wm * 64 + i * 16 + lm][q * 8];
            fAl[i] = *(const half8*)&Al[b][wm * 64 + i * 16 + lm][q * 8];
            fBh[i] = *(const half8*)&Bh[b][wn * 64 + i * 16 + lm][q * 8];
            fBl[i] = *(const half8*)&Bl[b][wn * 64 + i * 16 + lm][q * 8];
        }
#pragma unroll
        for (int i = 0; i < 4; ++i)
#pragma unroll
            for (int j = 0; j < 4; ++j)
                aH[i][j] = __builtin_amdgcn_mfma_f32_16x16x32_f16(fAh[i], fBh[j], aH[i][j], 0, 0, 0);
#pragma unroll
        for (int i = 0; i < 4; ++i)
#pragma unroll
            for (int j = 0; j < 4; ++j)
                aM[i][j] = __builtin_amdgcn_mfma_f32_16x16x32_f16(fAh[i], fBl[j], aM[i][j], 0, 0, 0);
#pragma unroll
        for (int i = 0; i < 4; ++i)
#pragma unroll
            for (int j = 0; j < 4; ++j)
                aM[i][j] = __builtin_amdgcn_mfma_f32_16x16x32_f16(fAl[i], fBh[j], aM[i][j], 0, 0, 0);
    }

    // Combine split accumulators: C = hi + mid/2048
    const float cM = 1.0f / 2048.0f;
#pragma unroll
    for (int i = 0; i < 4; ++i)
#pragma unroll
        for (int j = 0; j < 4; ++j)
            aH[i][j] = aH[i][j] + aM[i][j] * cM;

    float nm[4][4];
    if (EPI == 1) {
        __syncthreads();   // all frag reads done before aliasing Ah as sqv
#pragma unroll
        for (int i = 0; i < 4; ++i)
#pragma unroll
            for (int r = 0; r < 4; ++r) {
                float s = 0.f;
#pragma unroll
                for (int j = 0; j < 4; ++j) { float x = aH[i][j][r]; s = fmaf(x, x, s); }
#pragma unroll
                for (int off = 1; off < 16; off <<= 1) s += __shfl_xor(s, off, 16);
                if (lm == 0) sqv[(wm * 64 + i * 16 + q * 4 + r) * 2 + wn] = s;
            }
        __syncthreads();
#pragma unroll
        for (int i = 0; i < 4; ++i)
#pragma unroll
            for (int r = 0; r < 4; ++r) {
                const int rl = wm * 64 + i * 16 + q * 4 + r;
                nm[i][r] = fmaxf(sqrtf(sqv[rl * 2] + sqv[rl * 2 + 1]), 1e-12f);
            }
    }

    float bj[4] = {0.f, 0.f, 0.f, 0.f};
    if (EPI == 2 && wn == 0) {
#pragma unroll
        for (int j = 0; j < 4; ++j) bj[j] = bias[j * 16 + lm];
    }

#pragma unroll
    for (int i = 0; i < 4; ++i)
#pragma unroll
        for (int r = 0; r < 4; ++r) {
            const int m = mBase + wm * 64 + i * 16 + q * 4 + r;
            if (m < M) {
#pragma unroll
                for (int j = 0; j < 4; ++j) {
                    const int c = nBase + wn * 64 + j * 16 + lm;
                    float v = aH[i][j][r];
                    if (EPI == 0) { v = fmaxf(v, 0.f); outS[(size_t)m * No + c] = splitf(v); }
                    if (EPI == 1) { v = v / nm[i][r];  outS[(size_t)m * No + c] = splitf(v); }
                    if (EPI == 2) {
                        v += bj[j];
                        outF[(size_t)m * No + c] = v;
                        union { _Float16 f; unsigned short u; } cv; cv.f = (_Float16)v;
                        outH[(size_t)m * No + c] = cv.u;
                    }
                }
            }
        }
}

// ---------------------------------------------------------------------------
// Edge kernel: 128 edges/block, 16 lanes/edge, 8 edges/lane-group.
// Primary path gathers the fp16 p-table (8 B/lane per edge-half, 2x less
// traffic). Certified error bound: |score err| <= 2^-10 * sum |dw|*(|a|+|b|)
// (+2e-5 slack); if |gap| <= bound, re-gather fp32 and recompute exactly.
// Butterfly reductions are bit-identical across lanes -> branch is uniform
// within the 16-lane group.
// ---------------------------------------------------------------------------
#define EPB 128
__global__ __launch_bounds__(256, 4)
void edge_k(const unsigned short* __restrict__ pH, const float* __restrict__ p,
            const int* __restrict__ ei, const float* __restrict__ gum,
            const float* __restrict__ W2, const float* __restrict__ b2,
            float* __restrict__ out)
{
    __shared__ int   sidx[EPB];
    __shared__ int   didx[EPB];
    __shared__ float gl[2 * EPB];
    __shared__ float act[EPB];

    const int t  = threadIdx.x;
    const int e0 = blockIdx.x * EPB;

    if (t < EPB) sidx[t] = ei[e0 + t];
    else         didx[t - EPB] = ei[EROW + e0 + (t - EPB)];
    gl[t] = gum[(size_t)e0 * 2 + t];
    __syncthreads();

    const int j   = t & 15;
    const int grp = t >> 4;
    const float4 w0 = ld4(&W2[j * 4]);
    const float4 w1 = ld4(&W2[64 + j * 4]);
    const float4 dw = make_float4(fabsf(w0.x - w1.x), fabsf(w0.y - w1.y),
                                  fabsf(w0.z - w1.z), fabsf(w0.w - w1.w));
    const float b20 = b2[0], b21 = b2[1];

    union U8 { uint2 u; half4 h; };
    U8 ua[8], ub[8];
#pragma unroll
    for (int it = 0; it < 8; ++it) {
        const int el = grp * 8 + it;
        ua[it].u = *(const uint2*)&pH[(size_t)sidx[el] * 128 + j * 4];
        ub[it].u = *(const uint2*)&pH[(size_t)didx[el] * 128 + 64 + j * 4];
    }

#pragma unroll
    for (int it = 0; it < 8; ++it) {
        const int el = grp * 8 + it;
        const float a0 = (float)ua[it].h[0], a1 = (float)ua[it].h[1];
        const float a2 = (float)ua[it].h[2], a3 = (float)ua[it].h[3];
        const float c0 = (float)ub[it].h[0], c1 = (float)ub[it].h[1];
        const float c2 = (float)ub[it].h[2], c3 = (float)ub[it].h[3];
        const float r0 = fmaxf(a0 + c0, 0.f);
        const float r1 = fmaxf(a1 + c1, 0.f);
        const float r2 = fmaxf(a2 + c2, 0.f);
        const float r3 = fmaxf(a3 + c3, 0.f);
        float s0 = r0 * w0.x + r1 * w0.y + r2 * w0.z + r3 * w0.w;
        float s1 = r0 * w1.x + r1 * w1.y + r2 * w1.z + r3 * w1.w;
        float eb = dw.x * (fabsf(a0) + fabsf(c0)) + dw.y * (fabsf(a1) + fabsf(c1))
                 + dw.z * (fabsf(a2) + fabsf(c2)) + dw.w * (fabsf(a3) + fabsf(c3));
#pragma unroll
        for (int off = 1; off < 16; off <<= 1) {
            s0 += __shfl_xor(s0, off, 16);
            s1 += __shfl_xor(s1, off, 16);
            eb += __shfl_xor(eb, off, 16);
        }
        const float g0 = gl[el * 2], g1 = gl[el * 2 + 1];
        const float gap = (s0 + b20 + g0) - (s1 + b21 + g1);
        const float bound = eb * 0.0009765625f + 2e-5f;   // 2^-10 * eb + slack
        float av;
        if (fabsf(gap) > bound) {
            av = (gap >= 0.f) ? 1.f : 0.f;
        } else {
            // Exact fp32 recompute (rare; uniform within the 16-lane group).
            const float4 pa = ld4(&p[(size_t)sidx[el] * 128 + j * 4]);
            const float4 pb = ld4(&p[(size_t)didx[el] * 128 + 64 + j * 4]);
            const float q0 = fmaxf(pa.x + pb.x, 0.f);
            const float q1 = fmaxf(pa.y + pb.y, 0.f);
            const float q2 = fmaxf(pa.z + pb.z, 0.f);
            const float q3 = fmaxf(pa.w + pb.w, 0.f);
            float t0 = q0 * w0.x + q1 * w0.y + q2 * w0.z + q3 * w0.w;
            float t1 = q0 * w1.x + q1 * w1.y + q2 * w1.z + q3 * w1.w;
#pragma unroll
            for (int off = 1; off < 16; off <<= 1) {
                t0 += __shfl_xor(t0, off, 16);
                t1 += __shfl_xor(t1, off, 16);
            }
            const float ge = (t0 + b20 + g0) - (t1 + b21 + g1);
            av = (ge >= 0.f) ? 1.f : 0.f;
        }
        if (j == 0) act[el] = av;
    }
    __syncthreads();

    if (t < EPB) {
        const float a = act[t];
        const size_t e = (size_t)e0 + t;
        out[e]                  = a;
        out[EE + e]             = 1.f - a;
        out[2 * (size_t)EE + e] = 1.f - a;
    }
}

// ---------------------------------------------------------------------------
extern "C" void kernel_launch(void* const* d_in, const int* in_sizes, int n_in,
                              void* d_out, int out_size, void* d_ws, size_t ws_size,
                              hipStream_t stream)
{
    const float* trace  = (const float*)d_in[0];   // (2,100000,128)
    const float* W_lin  = (const float*)d_in[1];   // (256,256)
    const float* W_lin2 = (const float*)d_in[2];   // (128,256)
    const float* W_fc1  = (const float*)d_in[3];   // (64,256)
    const float* b_fc1  = (const float*)d_in[4];   // (64,)
    const float* W_fc2  = (const float*)d_in[5];   // (2,64)
    const float* b_fc2  = (const float*)d_in[6];   // (2,)
    const float* gum    = (const float*)d_in[7];   // (1600000,2)
    const int*   ei     = (const int*)  d_in[8];   // (2,4800000)
    float*       out    = (float*)d_out;           // (4800000,)

    // Workspace: h split-plane [NN x 256 dw] at 0 (102.4 MB); mvc split-plane
    // [NN x 128 dw] (51.2 MB); weight planes (459 KB). p (fp32, 51.2 MB) and
    // pH (fp16, 25.6 MB) overlay h's region (h dead after GEMM2). ~154 MB.
    char* ws = (char*)d_ws;
    unsigned*       hpl = (unsigned*)ws;
    unsigned*       mpl = (unsigned*)(ws + (size_t)NN * 256 * 4);
    unsigned*       W1i = (unsigned*)(ws + (size_t)NN * 256 * 4 + (size_t)NN * 128 * 4);
    unsigned*       W2i = W1i + 65536;
    unsigned*       W3i = W2i + 32768;
    float*          p   = (float*)ws;                                  // 51.2 MB
    unsigned short* pH  = (unsigned short*)(ws + (size_t)NN * 128 * 4); // +25.6 MB

    // Split weights into fp16 hi/lo interleaved planes.
    prep_w<<<448, 256, 0, stream>>>(W_lin, W_lin2, W_fc1, W1i, W2i, W3i);

    const int mB = (NN + 127) / 128;   // 782

    // h = relu(x @ W_lin^T), stored split
    gemm_mfma<0, 0><<<dim3(mB, 2), 256, 0, stream>>>(trace, W1i, nullptr, hpl, nullptr, nullptr, NN, 256, 256);
    // mvc = normalize_rows(h @ W_lin2^T), stored split
    gemm_mfma<1, 1><<<dim3(mB, 1), 256, 0, stream>>>(hpl, W2i, nullptr, mpl, nullptr, nullptr, NN, 256, 128);
    // p[n] = [W_fc1_left @ mvcn + b_fc1 | W_fc1_right @ mvcn], fp32 + fp16
    gemm_mfma<1, 2><<<dim3(mB, 1), 256, 0, stream>>>(mpl, W3i, b_fc1, nullptr, p, pH, NN, 128, 128);
    // per-edge score + hard mask (fp16 fast path, certified fp32 fallback)
    edge_k<<<EE / EPB, 256, 0, stream>>>(pH, p, ei, gum, W_fc2, b_fc2, out);
}